// Round 17
// baseline (945.937 us; speedup 1.0000x reference)
//
#include <hip/hip_runtime.h>
#include <math.h>

#define DIM     256
#define NROWS   32768
#define NCODES  8192
#define ZQ_ELEMS (NROWS * DIM)   // 8388608

#define CAND_MAX 64
// Filter on S = <bf16(z), bf16(w)> (argmin d == argmax(m - Q/2); |Q| <= 3.8e-6
// folded in). DS = 2.6e-4 in S-domain == validated 5e-4 v-domain + Q bound.
// DELAYED-by-one-chunk collection; exact recheck decides the final argmin.
#define DS       2.6e-4f
#define NCB      4
#define COLS_PER_CB (NCODES / NCB)   // 2048
#define BM 128                       // 4 waves x 32 rows
#define BN 32
#define CHUNKS (COLS_PER_CB / BN)    // 64
#define LCAP 1792                    // LDS ~39.9KB total -> 4 blocks/CU

typedef __attribute__((ext_vector_type(8))) short bf16x8;
typedef __attribute__((ext_vector_type(4))) float f32x4;

// ---------- explicit RNE float->bf16 ----------
__device__ __forceinline__ unsigned short bf16rne(float x) {
    unsigned u = __float_as_uint(x);
    unsigned r = (u + 0x7FFFu + ((u >> 16) & 1u)) >> 16;
    return (unsigned short)r;
}

// ---------- DPP 16-lane max reduce (VALU-only) ----------
template<int CTRL>
__device__ __forceinline__ float dppmax(float x) {
    int y = __builtin_amdgcn_update_dpp(0, __float_as_int(x), CTRL, 0xF, 0xF, false);
    return fmaxf(x, __int_as_float(y));
}
__device__ __forceinline__ float rowmax16(float x) {
    x = dppmax<0xB1>(x);    // xor1 (quad_perm 1,0,3,2)
    x = dppmax<0x4E>(x);    // xor2 (quad_perm 2,3,0,1)
    x = dppmax<0x141>(x);   // xor4 (row_half_mirror)
    x = dppmax<0x140>(x);   // xor8 (row_mirror)
    return x;
}

// ---------------- numpy pairwise-sum replication (128-block, 8 accumulators) ---------------
__device__ __forceinline__ float pw128_sq(const float* __restrict__ a) {
    float r[8];
#pragma unroll
    for (int j = 0; j < 8; ++j) r[j] = __fmul_rn(a[j], a[j]);
#pragma unroll
    for (int i = 8; i < 128; i += 8) {
#pragma unroll
        for (int j = 0; j < 8; ++j) r[j] = __fadd_rn(r[j], __fmul_rn(a[i + j], a[i + j]));
    }
    return __fadd_rn(__fadd_rn(__fadd_rn(r[0], r[1]), __fadd_rn(r[2], r[3])),
                     __fadd_rn(__fadd_rn(r[4], r[5]), __fadd_rn(r[6], r[7])));
}

// fused: P[r] = np.sum(x*x) (pairwise, bit-exact) + bf16 conversion write
// + (first 128 blocks) init of keys/cnt/flags.
__global__ __launch_bounds__(256) void rowsq_bf16_kernel(const float* __restrict__ src,
                                                         float* __restrict__ dst,
                                                         unsigned short* __restrict__ bdst,
                                                         unsigned long long* __restrict__ keys,
                                                         int* __restrict__ cnt,
                                                         int* __restrict__ flags) {
    __shared__ float tile[32][DIM + 1];
    const int row0 = blockIdx.x * 32;
    if (keys != nullptr && blockIdx.x < 128) {
        int gid = blockIdx.x * 256 + threadIdx.x;   // covers 32768
        keys[gid] = 0xFFFFFFFFFFFFFFFFull;
        cnt[gid] = 0;
        flags[gid] = 0;
    }
    for (int e = threadIdx.x; e < 32 * DIM / 4; e += 256) {
        int r = e >> 6, c4 = e & 63;
        float4 v = *(const float4*)&src[(size_t)(row0 + r) * DIM + c4 * 4];
        tile[r][c4 * 4 + 0] = v.x; tile[r][c4 * 4 + 1] = v.y;
        tile[r][c4 * 4 + 2] = v.z; tile[r][c4 * 4 + 3] = v.w;
        ushort4 o;
        o.x = bf16rne(v.x); o.y = bf16rne(v.y); o.z = bf16rne(v.z); o.w = bf16rne(v.w);
        ((ushort4*)bdst)[(size_t)(row0 + r) * 64 + c4] = o;
    }
    __syncthreads();
    if (threadIdx.x < 32) {
        const float* a = tile[threadIdx.x];
        float s0 = pw128_sq(a);
        float s1 = pw128_sq(a + 128);
        dst[row0 + threadIdx.x] = __fadd_rn(s0, s1);
    }
}

// ---------- async global->LDS, 16B/lane, wave-uniform LDS base ----------
__device__ __forceinline__ void gload_lds16(const void* g, void* l) {
    __builtin_amdgcn_global_load_lds(
        (const __attribute__((address_space(1))) unsigned int*)g,
        (__attribute__((address_space(3))) unsigned int*)l, 16, 0, 0);
}

// stage a contiguous 16KB region (4 waves x 4 x 1KB), read-side XOR swizzle
// pre-applied to the SOURCE address. involution: x ^ (((x>>9)&7)<<4)
__device__ __forceinline__ void stage16k(const char* gbase, char* lbase,
                                         int wave, int lane) {
#pragma unroll
    for (int it = 0; it < 4; ++it) {
        int ubase = it * 4096 + wave * 1024;          // wave-uniform, covers 16KB
        int loff  = ubase + (lane << 4);
        int goff  = loff ^ (((loff >> 9) & 7) << 4);
        gload_lds16(gbase + goff, lbase + ubase);
    }
}

#define WAIT_VM4()  asm volatile("s_waitcnt vmcnt(4)" ::: "memory")
#define WAIT_VM0()  asm volatile("s_waitcnt vmcnt(0)" ::: "memory")
#define LGKM0()     asm volatile("s_waitcnt lgkmcnt(0)" ::: "memory")
#define SBAR()      __builtin_amdgcn_s_barrier()
#define SCHEDB()    __builtin_amdgcn_sched_barrier(0)

// chunk body macro -> two-bank delayed collection, fully static indexing
#define CHUNK_BODY(CH, ACC, LMX, PACC, PLMX)                                      \
    do {                                                                          \
        const int ch_ = (CH);                                                     \
        const char* bb = (const char*)sbuf + ((ch_ & 1) << 14);                   \
        _Pragma("unroll")                                                         \
        for (int fr = 0; fr < 2; ++fr)                                            \
            _Pragma("unroll")                                                     \
            for (int fc = 0; fc < 2; ++fc) ACC[fr][fc] = (f32x4){0.f,0.f,0.f,0.f};\
        __builtin_amdgcn_s_setprio(1);                                            \
        _Pragma("unroll")                                                         \
        for (int kc = 0; kc < 8; ++kc) {                                          \
            bf16x8 bfr[2];                                                        \
            _Pragma("unroll")                                                     \
            for (int fc = 0; fc < 2; ++fc)                                        \
                bfr[fc] = *(const bf16x8*)(bb +                                   \
                    ((((fc * 16 + l15) << 9) + (kc << 6) + (lg << 4)) ^ swz));    \
            _Pragma("unroll")                                                     \
            for (int fr = 0; fr < 2; ++fr)                                        \
                _Pragma("unroll")                                                 \
                for (int fc = 0; fc < 2; ++fc)                                    \
                    ACC[fr][fc] = __builtin_amdgcn_mfma_f32_16x16x32_bf16(        \
                        afr[fr][kc], bfr[fc], ACC[fr][fc], 0, 0, 0);              \
        }                                                                         \
        __builtin_amdgcn_s_setprio(0);                                            \
        LGKM0();                                                                  \
        SCHEDB();                                                                 \
        SBAR();                                                                   \
        SCHEDB();                                                                 \
        if (ch_ + 2 < CHUNKS)                                                     \
            stage16k((const char*)(wb + ((size_t)(colbase + (ch_ + 2) * BN) << 8)), \
                     (char*)sbuf + ((ch_ & 1) << 14), wave, lane);                \
        _Pragma("unroll")                                                         \
        for (int fr = 0; fr < 2; ++fr)                                            \
            _Pragma("unroll")                                                     \
            for (int j = 0; j < 4; ++j) {                                         \
                LMX[fr][j] = fmaxf(ACC[fr][0][j], ACC[fr][1][j]);                 \
                rmx[fr][j] = fmaxf(rmx[fr][j], rowmax16(LMX[fr][j]));             \
            }                                                                     \
        if (ch_ > 0) {                                                            \
            const int code0 = colbase + (ch_ - 1) * BN;                           \
            _Pragma("unroll")                                                     \
            for (int fr = 0; fr < 2; ++fr)                                        \
                _Pragma("unroll")                                                 \
                for (int j = 0; j < 4; ++j) {                                     \
                    float thr = rmx[fr][j] - DS;                                  \
                    if (PLMX[fr][j] >= thr) {                                     \
                        const int rl = wave * 32 + fr * 16 + lg * 4 + j;          \
                        _Pragma("unroll")                                         \
                        for (int fc = 0; fc < 2; ++fc) {                          \
                            if (PACC[fr][fc][j] >= thr) {                         \
                                int code = code0 + fc * 16 + l15;                 \
                                unsigned s = atomicAdd(&lcnt, 1u);                \
                                if (s < LCAP) {                                   \
                                    list[s] = ((unsigned)rl << 13) | (unsigned)code; \
                                } else {                                          \
                                    int row = row0 + rl;                          \
                                    int slot = atomicAdd(&cnt[row], 1);           \
                                    if (slot < CAND_MAX)                          \
                                        cand[(size_t)row * CAND_MAX + slot] = code; \
                                    else flags[row] = 1;                          \
                                }                                                 \
                            }                                                     \
                        }                                                         \
                    }                                                             \
                }                                                                 \
        }                                                                         \
        if (ch_ + 2 < CHUNKS) { WAIT_VM4(); } else { WAIT_VM0(); }                \
        SCHEDB();                                                                 \
        SBAR();                                                                   \
        SCHEDB();                                                                 \
    } while (0)

// ---------------- MFMA bf16 filter: 4 waves x 32 rows, BN=32, S-max form -------------
// LDS ~39.9KB -> 4 blocks/CU (16 waves/CU, 4/SIMD — 2x r13 TLP). launch_bounds
// (256,4) caps VGPR at 128 (estimated need ~110, no spill). Schedule per chunk:
// MFMA -> LGKM0+SBAR -> stage(ch+2) -> {DPP max, collect(ch-1)} in staging
// shadow -> WAIT_VM4 -> SBAR. Counted vmcnt never drains mid-loop.
__global__ __launch_bounds__(256, 4) void mfma_filter_kernel(
    const unsigned short* __restrict__ zb, const unsigned short* __restrict__ wb,
    int* __restrict__ cnt, int* __restrict__ cand, int* __restrict__ flags) {
    __shared__ __align__(16) unsigned short sbuf[2 * BN * DIM];   // 32768 B
    __shared__ unsigned list[LCAP];                               // 7168 B
    __shared__ unsigned lcnt;

    const int tid  = threadIdx.x;
    const int wave = tid >> 6;
    const int lane = tid & 63;
    const int l15 = lane & 15, lg = lane >> 4;
    const int bid = blockIdx.x;
    const int r8  = bid & 7;
    const int cb  = r8 >> 1;                        // 0..3
    const int rb  = ((bid >> 3) << 1) | (r8 & 1);   // 0..255
    const int row0 = rb * BM;
    const int colbase = cb * COLS_PER_CB;
    const int swz = (l15 & 7) << 4;

    if (tid == 0) lcnt = 0;

    // ---- A fragments: direct global->registers, non-temporal ----
    bf16x8 afr[2][8];
    const unsigned short* za = zb + (size_t)(row0 + wave * 32 + l15) * DIM + lg * 8;
#pragma unroll
    for (int fr = 0; fr < 2; ++fr)
#pragma unroll
        for (int kc = 0; kc < 8; ++kc)
            afr[fr][kc] = __builtin_nontemporal_load(
                (const bf16x8*)(za + (size_t)fr * 16 * DIM + kc * 32));
    SCHEDB();   // pin A-load issue before staging (vmcnt arithmetic)

    // ---- prologue: issue B0, B1 ----
    stage16k((const char*)(wb + ((size_t)colbase << 8)), (char*)sbuf, wave, lane);
    stage16k((const char*)(wb + ((size_t)(colbase + BN) << 8)),
             (char*)sbuf + 16384, wave, lane);
    LGKM0();               // lcnt init visible
    WAIT_VM4();            // A(16)+B0(4) complete; B1 (4) outstanding
    SCHEDB();
    SBAR();                // blockwide: B0 ready
    SCHEDB();

    float rmx[2][4];       // running max per (fr,j) — uniform in l15 group
#pragma unroll
    for (int fr = 0; fr < 2; ++fr)
#pragma unroll
        for (int j = 0; j < 4; ++j) rmx[fr][j] = -INFINITY;

    f32x4 accE[2][2], accO[2][2];
    float lmxE[2][4], lmxO[2][4];

#pragma unroll 1
    for (int p = 0; p < CHUNKS; p += 2) {
        CHUNK_BODY(p,     accE, lmxE, accO, lmxO);
        CHUNK_BODY(p + 1, accO, lmxO, accE, lmxE);
    }

    // final chunk (63, in accO) vs the FINAL running max
    {
        const int code0 = colbase + (CHUNKS - 1) * BN;
#pragma unroll
        for (int fr = 0; fr < 2; ++fr)
#pragma unroll
            for (int j = 0; j < 4; ++j) {
                float thr = rmx[fr][j] - DS;
                if (lmxO[fr][j] >= thr) {
                    const int rl = wave * 32 + fr * 16 + lg * 4 + j;
#pragma unroll
                    for (int fc = 0; fc < 2; ++fc) {
                        if (accO[fr][fc][j] >= thr) {
                            int code = code0 + fc * 16 + l15;
                            unsigned s = atomicAdd(&lcnt, 1u);
                            if (s < LCAP) {
                                list[s] = ((unsigned)rl << 13) | (unsigned)code;
                            } else {
                                int row = row0 + rl;
                                int slot = atomicAdd(&cnt[row], 1);
                                if (slot < CAND_MAX)
                                    cand[(size_t)row * CAND_MAX + slot] = code;
                                else flags[row] = 1;
                            }
                        }
                    }
                }
            }
    }

    // ---- flush LDS candidate list to global ----
    LGKM0();
    SCHEDB();
    SBAR();
    SCHEDB();
    unsigned n = lcnt;
    if (n > LCAP) n = LCAP;
    for (unsigned i = tid; i < n; i += 256) {
        unsigned e = list[i];
        int rl = (int)(e >> 13);
        int code = (int)(e & 8191u);
        int row = row0 + rl;
        int slot = atomicAdd(&cnt[row], 1);
        if (slot < CAND_MAX) cand[(size_t)row * CAND_MAX + slot] = code;
        else flags[row] = 1;
    }
}

// ---------------- exact recheck: ascending-k fmaf chain, lexicographic atomicMin ----------------
__device__ __forceinline__ float exact_dot(const float* __restrict__ zr,
                                           const float* __restrict__ wj) {
    const f32x4* z4 = (const f32x4*)zr;
    const f32x4* w4 = (const f32x4*)wj;
    float m = 0.0f;
#pragma unroll 8
    for (int k4 = 0; k4 < 64; ++k4) {     // same ascending-k single chain, bit-exact
        f32x4 a = z4[k4], b = w4[k4];
        m = fmaf(a[0], b[0], m);
        m = fmaf(a[1], b[1], m);
        m = fmaf(a[2], b[2], m);
        m = fmaf(a[3], b[3], m);
    }
    return m;
}

// 32 slots/row; slot-stride loop handles n up to CAND_MAX.
__global__ __launch_bounds__(256) void recheck_kernel(
    const float* __restrict__ z, const float* __restrict__ w,
    const float* __restrict__ P, const float* __restrict__ Q,
    const int* __restrict__ cnt, const int* __restrict__ cand,
    const int* __restrict__ flags, unsigned long long* __restrict__ keys) {
    const int gid  = blockIdx.x * 256 + threadIdx.x;
    const int row  = gid >> 5;         // 32 slots per row
    const int slot = gid & 31;
    const float* zr = z + (size_t)row * DIM;

    if (flags[row]) {
        for (int j = slot; j < NCODES; j += 32) {
            float m = exact_dot(zr, w + (size_t)j * DIM);
            float d = __fsub_rn(__fadd_rn(P[row], Q[j]), __fmul_rn(2.0f, m));
            unsigned long long key =
                ((unsigned long long)__float_as_uint(d) << 32) | (unsigned)j;
            atomicMin(&keys[row], key);
        }
        return;
    }
    int n = cnt[row]; if (n > CAND_MAX) n = CAND_MAX;
    for (int s = slot; s < n; s += 32) {
        const int j = cand[(size_t)row * CAND_MAX + s];
        float m = exact_dot(zr, w + (size_t)j * DIM);
        float d = __fsub_rn(__fadd_rn(P[row], Q[j]), __fmul_rn(2.0f, m));
        unsigned long long key = ((unsigned long long)__float_as_uint(d) << 32) | (unsigned)j;
        atomicMin(&keys[row], key);
    }
}

// ---------------- gather z_q, write z_q_st + idx_f (fused finalize), loss partials -------------
__global__ __launch_bounds__(256) void gather_loss_kernel(
    const float* __restrict__ z, const float* __restrict__ w,
    const unsigned long long* __restrict__ keys, const int* __restrict__ idx_i,
    float* __restrict__ zq_out, float* __restrict__ idx_f,
    double* __restrict__ partial) {
    __shared__ double red[256];
    const int t    = blockIdx.x * 256 + threadIdx.x;
    const int base = t * 4;
    const int row  = base >> 8;
    const int c    = base & 255;
    int code;
    if (keys != nullptr) code = (int)(unsigned)(keys[row] & 0xFFFFFFFFull);
    else                 code = idx_i[row];
    if (c == 0) idx_f[row] = (float)code;
    f32x4 zv = __builtin_nontemporal_load((const f32x4*)&z[base]);
    f32x4 wv = *(const f32x4*)&w[(size_t)code * DIM + c];
    float o[4];
    double s = 0.0;
#pragma unroll
    for (int j = 0; j < 4; ++j) {
        float diff = __fsub_rn(wv[j], zv[j]);
        o[j] = __fadd_rn(zv[j], diff);
        double dd = (double)diff;
        s += dd * dd;
    }
    f32x4 ov = { o[0], o[1], o[2], o[3] };
    __builtin_nontemporal_store(ov, (f32x4*)&zq_out[base]);
    red[threadIdx.x] = s;
    __syncthreads();
    for (int st = 128; st > 0; st >>= 1) {
        if (threadIdx.x < st) red[threadIdx.x] += red[threadIdx.x + st];
        __syncthreads();
    }
    if (threadIdx.x == 0) partial[blockIdx.x] = red[0];
}

__global__ __launch_bounds__(256) void loss_final_kernel(const double* __restrict__ partial,
                                                         float* __restrict__ loss_out) {
    __shared__ double red[256];
    double s = 0.0;
    for (int i = threadIdx.x; i < 8192; i += 256) s += partial[i];
    red[threadIdx.x] = s;
    __syncthreads();
    for (int st = 128; st > 0; st >>= 1) {
        if (threadIdx.x < st) red[threadIdx.x] += red[threadIdx.x + st];
        __syncthreads();
    }
    if (threadIdx.x == 0)
        loss_out[0] = (float)(1.25 * red[0] / (double)ZQ_ELEMS);
}

// ---------------- small-ws fallback: round-2 exact VALU kernel ----------------
#define FB_BM 128
#define FB_BN 128
#define FB_BK 32
#define FB_PITCH 132

__global__ __launch_bounds__(256, 4) void vq_partial_kernel(
    const float* __restrict__ z, const float* __restrict__ w,
    const float* __restrict__ P, const float* __restrict__ Q,
    float* __restrict__ cand_d, int* __restrict__ cand_i) {
    __shared__ float As[FB_BK][FB_PITCH];
    __shared__ float Bs[FB_BK][FB_PITCH];
    const int tid  = threadIdx.x;
    const int rb   = blockIdx.x >> 2;
    const int cb   = blockIdx.x & 3;
    const int row0 = rb * FB_BM;
    const int colbase = cb * COLS_PER_CB;
    const int rg = tid >> 4;
    const int cg = tid & 15;
    float Pr[8];
#pragma unroll
    for (int i = 0; i < 8; ++i) Pr[i] = P[row0 + rg * 8 + i];
    float bestD[8]; int bestI[8];
#pragma unroll
    for (int i = 0; i < 8; ++i) { bestD[i] = INFINITY; bestI[i] = 0; }
    for (int ct = 0; ct < COLS_PER_CB; ct += FB_BN) {
        const int c0 = colbase + ct;
        float acc[8][8];
#pragma unroll
        for (int i = 0; i < 8; ++i)
#pragma unroll
            for (int j = 0; j < 8; ++j) acc[i][j] = 0.0f;
        for (int kc = 0; kc < DIM; kc += FB_BK) {
            __syncthreads();
#pragma unroll
            for (int it = 0; it < 4; ++it) {
                int u = it * 256 + tid;
                int r = u >> 3, kg = u & 7;
                float4 a = *(const float4*)&z[(size_t)(row0 + r) * DIM + kc + kg * 4];
                As[kg * 4 + 0][r] = a.x; As[kg * 4 + 1][r] = a.y;
                As[kg * 4 + 2][r] = a.z; As[kg * 4 + 3][r] = a.w;
                float4 b = *(const float4*)&w[(size_t)(c0 + r) * DIM + kc + kg * 4];
                Bs[kg * 4 + 0][r] = b.x; Bs[kg * 4 + 1][r] = b.y;
                Bs[kg * 4 + 2][r] = b.z; Bs[kg * 4 + 3][r] = b.w;
            }
            __syncthreads();
#pragma unroll
            for (int k = 0; k < FB_BK; ++k) {
                float av[8], bv[8];
                { float4 t = *(const float4*)&As[k][rg * 8];
                  av[0]=t.x; av[1]=t.y; av[2]=t.z; av[3]=t.w; }
                { float4 t = *(const float4*)&As[k][rg * 8 + 4];
                  av[4]=t.x; av[5]=t.y; av[6]=t.z; av[7]=t.w; }
                { float4 t = *(const float4*)&Bs[k][cg * 4];
                  bv[0]=t.x; bv[1]=t.y; bv[2]=t.z; bv[3]=t.w; }
                { float4 t = *(const float4*)&Bs[k][cg * 4 + 64];
                  bv[4]=t.x; bv[5]=t.y; bv[6]=t.z; bv[7]=t.w; }
#pragma unroll
                for (int i = 0; i < 8; ++i)
#pragma unroll
                    for (int j = 0; j < 8; ++j)
                        acc[i][j] = fmaf(av[i], bv[j], acc[i][j]);
            }
        }
        float qv[8];
        { float4 t = *(const float4*)&Q[c0 + cg * 4];
          qv[0]=t.x; qv[1]=t.y; qv[2]=t.z; qv[3]=t.w; }
        { float4 t = *(const float4*)&Q[c0 + 64 + cg * 4];
          qv[4]=t.x; qv[5]=t.y; qv[6]=t.z; qv[7]=t.w; }
#pragma unroll
        for (int i = 0; i < 8; ++i)
#pragma unroll
            for (int j = 0; j < 8; ++j) {
                float d = __fsub_rn(__fadd_rn(Pr[i], qv[j]), __fmul_rn(2.0f, acc[i][j]));
                int code = c0 + ((j < 4) ? (cg * 4 + j) : (64 + cg * 4 + (j - 4)));
                if (d < bestD[i]) { bestD[i] = d; bestI[i] = code; }
            }
    }
#pragma unroll
    for (int off = 1; off < 16; off <<= 1)
#pragma unroll
        for (int i = 0; i < 8; ++i) {
            float od = __shfl_xor(bestD[i], off);
            int   oi = __shfl_xor(bestI[i], off);
            if (od < bestD[i] || (od == bestD[i] && oi < bestI[i])) {
                bestD[i] = od; bestI[i] = oi;
            }
        }
    if (cg == 0)
#pragma unroll
        for (int i = 0; i < 8; ++i) {
            int row = row0 + rg * 8 + i;
            cand_d[cb * NROWS + row] = bestD[i];
            cand_i[cb * NROWS + row] = bestI[i];
        }
}

__global__ __launch_bounds__(256) void argmin_reduce_kernel(
    const float* __restrict__ cand_d, const int* __restrict__ cand_i,
    int* __restrict__ idx_i, float* __restrict__ idx_f) {
    const int row = blockIdx.x * 256 + threadIdx.x;
    float bd = cand_d[row];
    int   bi = cand_i[row];
#pragma unroll
    for (int cb = 1; cb < NCB; ++cb) {
        float d = cand_d[cb * NROWS + row];
        int   ii = cand_i[cb * NROWS + row];
        if (d < bd || (d == bd && ii < bi)) { bd = d; bi = ii; }
    }
    idx_i[row] = bi;
    idx_f[row] = (float)bi;
}

extern "C" void kernel_launch(void* const* d_in, const int* in_sizes, int n_in,
                              void* d_out, int out_size, void* d_ws, size_t ws_size,
                              hipStream_t stream) {
    const float* z = (const float*)d_in[0];   // [32768, 256]
    const float* w = (const float*)d_in[1];   // [8192, 256]
    float* out = (float*)d_out;               // [zq 8388608][loss 1][idx 32768]

    float* ws = (float*)d_ws;
    unsigned short* zb = (unsigned short*)ws;                       // 8388608 bf16
    unsigned short* wb = (unsigned short*)(ws + 4194304);           // 2097152 bf16
    float*  P       = ws + 4194304 + 1048576;                       // 32768
    float*  Q       = P + NROWS;                                    // 8192
    int*    idx_i   = (int*)(Q + NCODES);                           // 32768
    double* partial = (double*)(idx_i + NROWS);                     // 8192 dbl
    unsigned long long* keys = (unsigned long long*)(partial + 8192); // 32768 ull
    int*    cnt     = (int*)(keys + NROWS);                         // 32768
    int*    flags   = cnt + NROWS;                                  // 32768
    int*    cand    = flags + NROWS;                                // 32768*64
    const size_t NEED = ((size_t)(4194304 + 1048576 + 32768 + 8192 + 32768 + 16384 + 65536
                                  + 32768 + 32768 + 2097152)) * 4;  // ~30.2 MB

    if (ws_size >= NEED) {
        rowsq_bf16_kernel<<<NROWS / 32, 256, 0, stream>>>(z, P, zb, keys, cnt, flags);
        rowsq_bf16_kernel<<<NCODES / 32, 256, 0, stream>>>(w, Q, wb, nullptr, nullptr, nullptr);
        mfma_filter_kernel<<<(NROWS / BM) * NCB, 256, 0, stream>>>(zb, wb, cnt, cand, flags);
        recheck_kernel<<<NROWS * 32 / 256, 256, 0, stream>>>(z, w, P, Q, cnt, cand,
                                                             flags, keys);
        gather_loss_kernel<<<ZQ_ELEMS / (256 * 4), 256, 0, stream>>>(
            z, w, keys, nullptr, out, out + ZQ_ELEMS + 1, partial);
    } else {
        rowsq_bf16_kernel<<<NROWS / 32, 256, 0, stream>>>(z, P, zb, nullptr, nullptr, nullptr);
        rowsq_bf16_kernel<<<NCODES / 32, 256, 0, stream>>>(w, Q, wb, nullptr, nullptr, nullptr);
        float* cand_d = (float*)(partial + 8192);
        int*   cand_i = (int*)(cand_d + NCB * NROWS);
        vq_partial_kernel<<<(NROWS / FB_BM) * NCB, 256, 0, stream>>>(z, w, P, Q, cand_d, cand_i);
        argmin_reduce_kernel<<<NROWS / 256, 256, 0, stream>>>(cand_d, cand_i, idx_i,
                                                              out + ZQ_ELEMS + 1);
        gather_loss_kernel<<<ZQ_ELEMS / (256 * 4), 256, 0, stream>>>(
            z, w, nullptr, idx_i, out, out + ZQ_ELEMS + 1, partial);
    }

    loss_final_kernel<<<1, 256, 0, stream>>>(partial, out + ZQ_ELEMS);
}

// Round 18
// 542.565 us; speedup vs baseline: 1.7435x; 1.7435x over previous
//
#include <hip/hip_runtime.h>
#include <math.h>

#define DIM     256
#define NROWS   32768
#define NCODES  8192
#define ZQ_ELEMS (NROWS * DIM)   // 8388608

#define CAND_MAX 64
// Filter on S = <bf16(z), bf16(w)> (argmin d == argmax(m - Q/2); |Q| <= 3.8e-6
// folded in). DS = 2.6e-4 in S-domain == validated 5e-4 v-domain + Q bound.
// DELAYED-by-one-chunk collection; exact recheck decides the final argmin.
#define DS       2.6e-4f
#define NCB      4
#define COLS_PER_CB (NCODES / NCB)   // 2048
#define BM 128                       // 4 waves x 32 rows
#define BN 32
#define CHUNKS (COLS_PER_CB / BN)    // 64
#define LCAP 1792                    // LDS ~39.9KB total -> 4 blocks/CU

typedef __attribute__((ext_vector_type(8))) short bf16x8;
typedef __attribute__((ext_vector_type(4))) float f32x4;

// ---------- explicit RNE float->bf16 ----------
__device__ __forceinline__ unsigned short bf16rne(float x) {
    unsigned u = __float_as_uint(x);
    unsigned r = (u + 0x7FFFu + ((u >> 16) & 1u)) >> 16;
    return (unsigned short)r;
}

// ---------- DPP 16-lane max reduce (VALU-only) ----------
template<int CTRL>
__device__ __forceinline__ float dppmax(float x) {
    int y = __builtin_amdgcn_update_dpp(0, __float_as_int(x), CTRL, 0xF, 0xF, false);
    return fmaxf(x, __int_as_float(y));
}
__device__ __forceinline__ float rowmax16(float x) {
    x = dppmax<0xB1>(x);    // xor1 (quad_perm 1,0,3,2)
    x = dppmax<0x4E>(x);    // xor2 (quad_perm 2,3,0,1)
    x = dppmax<0x141>(x);   // xor4 (row_half_mirror)
    x = dppmax<0x140>(x);   // xor8 (row_mirror)
    return x;
}

// ---------------- numpy pairwise-sum replication (128-block, 8 accumulators) ---------------
__device__ __forceinline__ float pw128_sq(const float* __restrict__ a) {
    float r[8];
#pragma unroll
    for (int j = 0; j < 8; ++j) r[j] = __fmul_rn(a[j], a[j]);
#pragma unroll
    for (int i = 8; i < 128; i += 8) {
#pragma unroll
        for (int j = 0; j < 8; ++j) r[j] = __fadd_rn(r[j], __fmul_rn(a[i + j], a[i + j]));
    }
    return __fadd_rn(__fadd_rn(__fadd_rn(r[0], r[1]), __fadd_rn(r[2], r[3])),
                     __fadd_rn(__fadd_rn(r[4], r[5]), __fadd_rn(r[6], r[7])));
}

// fused: P[r] = np.sum(x*x) (pairwise, bit-exact) + bf16 conversion write
// + (first 128 blocks) init of keys/cnt/flags.
__global__ __launch_bounds__(256) void rowsq_bf16_kernel(const float* __restrict__ src,
                                                         float* __restrict__ dst,
                                                         unsigned short* __restrict__ bdst,
                                                         unsigned long long* __restrict__ keys,
                                                         int* __restrict__ cnt,
                                                         int* __restrict__ flags) {
    __shared__ float tile[32][DIM + 1];
    const int row0 = blockIdx.x * 32;
    if (keys != nullptr && blockIdx.x < 128) {
        int gid = blockIdx.x * 256 + threadIdx.x;   // covers 32768
        keys[gid] = 0xFFFFFFFFFFFFFFFFull;
        cnt[gid] = 0;
        flags[gid] = 0;
    }
    for (int e = threadIdx.x; e < 32 * DIM / 4; e += 256) {
        int r = e >> 6, c4 = e & 63;
        float4 v = *(const float4*)&src[(size_t)(row0 + r) * DIM + c4 * 4];
        tile[r][c4 * 4 + 0] = v.x; tile[r][c4 * 4 + 1] = v.y;
        tile[r][c4 * 4 + 2] = v.z; tile[r][c4 * 4 + 3] = v.w;
        ushort4 o;
        o.x = bf16rne(v.x); o.y = bf16rne(v.y); o.z = bf16rne(v.z); o.w = bf16rne(v.w);
        ((ushort4*)bdst)[(size_t)(row0 + r) * 64 + c4] = o;
    }
    __syncthreads();
    if (threadIdx.x < 32) {
        const float* a = tile[threadIdx.x];
        float s0 = pw128_sq(a);
        float s1 = pw128_sq(a + 128);
        dst[row0 + threadIdx.x] = __fadd_rn(s0, s1);
    }
}

// ---------- async global->LDS, 16B/lane, wave-uniform LDS base ----------
__device__ __forceinline__ void gload_lds16(const void* g, void* l) {
    __builtin_amdgcn_global_load_lds(
        (const __attribute__((address_space(1))) unsigned int*)g,
        (__attribute__((address_space(3))) unsigned int*)l, 16, 0, 0);
}

// stage a contiguous 16KB region (4 waves x 4 x 1KB), read-side XOR swizzle
// pre-applied to the SOURCE address. involution: x ^ (((x>>9)&7)<<4)
__device__ __forceinline__ void stage16k(const char* gbase, char* lbase,
                                         int wave, int lane) {
#pragma unroll
    for (int it = 0; it < 4; ++it) {
        int ubase = it * 4096 + wave * 1024;          // wave-uniform, covers 16KB
        int loff  = ubase + (lane << 4);
        int goff  = loff ^ (((loff >> 9) & 7) << 4);
        gload_lds16(gbase + goff, lbase + ubase);
    }
}

#define WAIT_VM4()  asm volatile("s_waitcnt vmcnt(4)" ::: "memory")
#define WAIT_VM0()  asm volatile("s_waitcnt vmcnt(0)" ::: "memory")
#define LGKM0()     asm volatile("s_waitcnt lgkmcnt(0)" ::: "memory")
#define SBAR()      __builtin_amdgcn_s_barrier()
#define SCHEDB()    __builtin_amdgcn_sched_barrier(0)

// chunk body macro -> two-bank delayed collection, fully static indexing
#define CHUNK_BODY(CH, ACC, LMX, PACC, PLMX)                                      \
    do {                                                                          \
        const int ch_ = (CH);                                                     \
        const char* bb = (const char*)sbuf + ((ch_ & 1) << 14);                   \
        _Pragma("unroll")                                                         \
        for (int fr = 0; fr < 2; ++fr)                                            \
            _Pragma("unroll")                                                     \
            for (int fc = 0; fc < 2; ++fc) ACC[fr][fc] = (f32x4){0.f,0.f,0.f,0.f};\
        __builtin_amdgcn_s_setprio(1);                                            \
        _Pragma("unroll")                                                         \
        for (int kc = 0; kc < 8; ++kc) {                                          \
            bf16x8 bfr[2];                                                        \
            _Pragma("unroll")                                                     \
            for (int fc = 0; fc < 2; ++fc)                                        \
                bfr[fc] = *(const bf16x8*)(bb +                                   \
                    ((((fc * 16 + l15) << 9) + (kc << 6) + (lg << 4)) ^ swz));    \
            _Pragma("unroll")                                                     \
            for (int fr = 0; fr < 2; ++fr)                                        \
                _Pragma("unroll")                                                 \
                for (int fc = 0; fc < 2; ++fc)                                    \
                    ACC[fr][fc] = __builtin_amdgcn_mfma_f32_16x16x32_bf16(        \
                        afr[fr][kc], bfr[fc], ACC[fr][fc], 0, 0, 0);              \
        }                                                                         \
        __builtin_amdgcn_s_setprio(0);                                            \
        LGKM0();                                                                  \
        SCHEDB();                                                                 \
        SBAR();                                                                   \
        SCHEDB();                                                                 \
        if (ch_ + 2 < CHUNKS)                                                     \
            stage16k((const char*)(wb + ((size_t)(colbase + (ch_ + 2) * BN) << 8)), \
                     (char*)sbuf + ((ch_ & 1) << 14), wave, lane);                \
        _Pragma("unroll")                                                         \
        for (int fr = 0; fr < 2; ++fr)                                            \
            _Pragma("unroll")                                                     \
            for (int j = 0; j < 4; ++j) {                                         \
                LMX[fr][j] = fmaxf(ACC[fr][0][j], ACC[fr][1][j]);                 \
                rmx[fr][j] = fmaxf(rmx[fr][j], rowmax16(LMX[fr][j]));             \
            }                                                                     \
        if (ch_ > 0) {                                                            \
            const int code0 = colbase + (ch_ - 1) * BN;                           \
            _Pragma("unroll")                                                     \
            for (int fr = 0; fr < 2; ++fr)                                        \
                _Pragma("unroll")                                                 \
                for (int j = 0; j < 4; ++j) {                                     \
                    float thr = rmx[fr][j] - DS;                                  \
                    if (PLMX[fr][j] >= thr) {                                     \
                        const int rl = wave * 32 + fr * 16 + lg * 4 + j;          \
                        _Pragma("unroll")                                         \
                        for (int fc = 0; fc < 2; ++fc) {                          \
                            if (PACC[fr][fc][j] >= thr) {                         \
                                int code = code0 + fc * 16 + l15;                 \
                                unsigned s = atomicAdd(&lcnt, 1u);                \
                                if (s < LCAP) {                                   \
                                    list[s] = ((unsigned)rl << 13) | (unsigned)code; \
                                } else {                                          \
                                    int row = row0 + rl;                          \
                                    int slot = atomicAdd(&cnt[row], 1);           \
                                    if (slot < CAND_MAX)                          \
                                        cand[(size_t)row * CAND_MAX + slot] = code; \
                                    else flags[row] = 1;                          \
                                }                                                 \
                            }                                                     \
                        }                                                         \
                    }                                                             \
                }                                                                 \
        }                                                                         \
        if (ch_ + 2 < CHUNKS) { WAIT_VM4(); } else { WAIT_VM0(); }                \
        SCHEDB();                                                                 \
        SBAR();                                                                   \
        SCHEDB();                                                                 \
    } while (0)

// ---------------- MFMA bf16 filter: 4 waves x 32 rows, BN=32, S-max form -------------
// launch_bounds(256,2): VGPR cap 128 (empirical hipcc law: cap = 256/arg; arg=4
// forced 64 and spilled in r14/r17). Honest need ~100 -> no spill. LDS 40448 B
// -> hardware can resident 4 blocks/CU (161792 <= 163840) = 4 waves/SIMD.
__global__ __launch_bounds__(256, 2) void mfma_filter_kernel(
    const unsigned short* __restrict__ zb, const unsigned short* __restrict__ wb,
    int* __restrict__ cnt, int* __restrict__ cand, int* __restrict__ flags) {
    __shared__ __align__(16) unsigned short sbuf[2 * BN * DIM];   // 32768 B
    __shared__ unsigned list[LCAP];                               // 7168 B
    __shared__ unsigned lcnt;

    const int tid  = threadIdx.x;
    const int wave = tid >> 6;
    const int lane = tid & 63;
    const int l15 = lane & 15, lg = lane >> 4;
    const int bid = blockIdx.x;
    const int r8  = bid & 7;
    const int cb  = r8 >> 1;                        // 0..3
    const int rb  = ((bid >> 3) << 1) | (r8 & 1);   // 0..255
    const int row0 = rb * BM;
    const int colbase = cb * COLS_PER_CB;
    const int swz = (l15 & 7) << 4;

    if (tid == 0) lcnt = 0;

    // ---- A fragments: direct global->registers, non-temporal ----
    bf16x8 afr[2][8];
    const unsigned short* za = zb + (size_t)(row0 + wave * 32 + l15) * DIM + lg * 8;
#pragma unroll
    for (int fr = 0; fr < 2; ++fr)
#pragma unroll
        for (int kc = 0; kc < 8; ++kc)
            afr[fr][kc] = __builtin_nontemporal_load(
                (const bf16x8*)(za + (size_t)fr * 16 * DIM + kc * 32));
    SCHEDB();   // pin A-load issue before staging (vmcnt arithmetic)

    // ---- prologue: issue B0, B1 ----
    stage16k((const char*)(wb + ((size_t)colbase << 8)), (char*)sbuf, wave, lane);
    stage16k((const char*)(wb + ((size_t)(colbase + BN) << 8)),
             (char*)sbuf + 16384, wave, lane);
    LGKM0();               // lcnt init visible
    WAIT_VM4();            // A(16)+B0(4) complete; B1 (4) outstanding
    SCHEDB();
    SBAR();                // blockwide: B0 ready
    SCHEDB();

    float rmx[2][4];       // running max per (fr,j) — uniform in l15 group
#pragma unroll
    for (int fr = 0; fr < 2; ++fr)
#pragma unroll
        for (int j = 0; j < 4; ++j) rmx[fr][j] = -INFINITY;

    f32x4 accE[2][2], accO[2][2];
    float lmxE[2][4], lmxO[2][4];

#pragma unroll 1
    for (int p = 0; p < CHUNKS; p += 2) {
        CHUNK_BODY(p,     accE, lmxE, accO, lmxO);
        CHUNK_BODY(p + 1, accO, lmxO, accE, lmxE);
    }

    // final chunk (63, in accO) vs the FINAL running max
    {
        const int code0 = colbase + (CHUNKS - 1) * BN;
#pragma unroll
        for (int fr = 0; fr < 2; ++fr)
#pragma unroll
            for (int j = 0; j < 4; ++j) {
                float thr = rmx[fr][j] - DS;
                if (lmxO[fr][j] >= thr) {
                    const int rl = wave * 32 + fr * 16 + lg * 4 + j;
#pragma unroll
                    for (int fc = 0; fc < 2; ++fc) {
                        if (accO[fr][fc][j] >= thr) {
                            int code = code0 + fc * 16 + l15;
                            unsigned s = atomicAdd(&lcnt, 1u);
                            if (s < LCAP) {
                                list[s] = ((unsigned)rl << 13) | (unsigned)code;
                            } else {
                                int row = row0 + rl;
                                int slot = atomicAdd(&cnt[row], 1);
                                if (slot < CAND_MAX)
                                    cand[(size_t)row * CAND_MAX + slot] = code;
                                else flags[row] = 1;
                            }
                        }
                    }
                }
            }
    }

    // ---- flush LDS candidate list to global ----
    LGKM0();
    SCHEDB();
    SBAR();
    SCHEDB();
    unsigned n = lcnt;
    if (n > LCAP) n = LCAP;
    for (unsigned i = tid; i < n; i += 256) {
        unsigned e = list[i];
        int rl = (int)(e >> 13);
        int code = (int)(e & 8191u);
        int row = row0 + rl;
        int slot = atomicAdd(&cnt[row], 1);
        if (slot < CAND_MAX) cand[(size_t)row * CAND_MAX + slot] = code;
        else flags[row] = 1;
    }
}

// ---------------- exact recheck: ascending-k fmaf chain, lexicographic atomicMin ----------------
__device__ __forceinline__ float exact_dot(const float* __restrict__ zr,
                                           const float* __restrict__ wj) {
    const f32x4* z4 = (const f32x4*)zr;
    const f32x4* w4 = (const f32x4*)wj;
    float m = 0.0f;
#pragma unroll 8
    for (int k4 = 0; k4 < 64; ++k4) {     // same ascending-k single chain, bit-exact
        f32x4 a = z4[k4], b = w4[k4];
        m = fmaf(a[0], b[0], m);
        m = fmaf(a[1], b[1], m);
        m = fmaf(a[2], b[2], m);
        m = fmaf(a[3], b[3], m);
    }
    return m;
}

// 32 slots/row; slot-stride loop handles n up to CAND_MAX.
__global__ __launch_bounds__(256) void recheck_kernel(
    const float* __restrict__ z, const float* __restrict__ w,
    const float* __restrict__ P, const float* __restrict__ Q,
    const int* __restrict__ cnt, const int* __restrict__ cand,
    const int* __restrict__ flags, unsigned long long* __restrict__ keys) {
    const int gid  = blockIdx.x * 256 + threadIdx.x;
    const int row  = gid >> 5;         // 32 slots per row
    const int slot = gid & 31;
    const float* zr = z + (size_t)row * DIM;

    if (flags[row]) {
        for (int j = slot; j < NCODES; j += 32) {
            float m = exact_dot(zr, w + (size_t)j * DIM);
            float d = __fsub_rn(__fadd_rn(P[row], Q[j]), __fmul_rn(2.0f, m));
            unsigned long long key =
                ((unsigned long long)__float_as_uint(d) << 32) | (unsigned)j;
            atomicMin(&keys[row], key);
        }
        return;
    }
    int n = cnt[row]; if (n > CAND_MAX) n = CAND_MAX;
    for (int s = slot; s < n; s += 32) {
        const int j = cand[(size_t)row * CAND_MAX + s];
        float m = exact_dot(zr, w + (size_t)j * DIM);
        float d = __fsub_rn(__fadd_rn(P[row], Q[j]), __fmul_rn(2.0f, m));
        unsigned long long key = ((unsigned long long)__float_as_uint(d) << 32) | (unsigned)j;
        atomicMin(&keys[row], key);
    }
}

// ---------------- gather z_q, write z_q_st + idx_f (fused finalize), loss partials -------------
__global__ __launch_bounds__(256) void gather_loss_kernel(
    const float* __restrict__ z, const float* __restrict__ w,
    const unsigned long long* __restrict__ keys, const int* __restrict__ idx_i,
    float* __restrict__ zq_out, float* __restrict__ idx_f,
    double* __restrict__ partial) {
    __shared__ double red[256];
    const int t    = blockIdx.x * 256 + threadIdx.x;
    const int base = t * 4;
    const int row  = base >> 8;
    const int c    = base & 255;
    int code;
    if (keys != nullptr) code = (int)(unsigned)(keys[row] & 0xFFFFFFFFull);
    else                 code = idx_i[row];
    if (c == 0) idx_f[row] = (float)code;
    f32x4 zv = __builtin_nontemporal_load((const f32x4*)&z[base]);
    f32x4 wv = *(const f32x4*)&w[(size_t)code * DIM + c];
    float o[4];
    double s = 0.0;
#pragma unroll
    for (int j = 0; j < 4; ++j) {
        float diff = __fsub_rn(wv[j], zv[j]);
        o[j] = __fadd_rn(zv[j], diff);
        double dd = (double)diff;
        s += dd * dd;
    }
    f32x4 ov = { o[0], o[1], o[2], o[3] };
    __builtin_nontemporal_store(ov, (f32x4*)&zq_out[base]);
    red[threadIdx.x] = s;
    __syncthreads();
    for (int st = 128; st > 0; st >>= 1) {
        if (threadIdx.x < st) red[threadIdx.x] += red[threadIdx.x + st];
        __syncthreads();
    }
    if (threadIdx.x == 0) partial[blockIdx.x] = red[0];
}

__global__ __launch_bounds__(256) void loss_final_kernel(const double* __restrict__ partial,
                                                         float* __restrict__ loss_out) {
    __shared__ double red[256];
    double s = 0.0;
    for (int i = threadIdx.x; i < 8192; i += 256) s += partial[i];
    red[threadIdx.x] = s;
    __syncthreads();
    for (int st = 128; st > 0; st >>= 1) {
        if (threadIdx.x < st) red[threadIdx.x] += red[threadIdx.x + st];
        __syncthreads();
    }
    if (threadIdx.x == 0)
        loss_out[0] = (float)(1.25 * red[0] / (double)ZQ_ELEMS);
}

// ---------------- small-ws fallback: round-2 exact VALU kernel ----------------
#define FB_BM 128
#define FB_BN 128
#define FB_BK 32
#define FB_PITCH 132

__global__ __launch_bounds__(256, 4) void vq_partial_kernel(
    const float* __restrict__ z, const float* __restrict__ w,
    const float* __restrict__ P, const float* __restrict__ Q,
    float* __restrict__ cand_d, int* __restrict__ cand_i) {
    __shared__ float As[FB_BK][FB_PITCH];
    __shared__ float Bs[FB_BK][FB_PITCH];
    const int tid  = threadIdx.x;
    const int rb   = blockIdx.x >> 2;
    const int cb   = blockIdx.x & 3;
    const int row0 = rb * FB_BM;
    const int colbase = cb * COLS_PER_CB;
    const int rg = tid >> 4;
    const int cg = tid & 15;
    float Pr[8];
#pragma unroll
    for (int i = 0; i < 8; ++i) Pr[i] = P[row0 + rg * 8 + i];
    float bestD[8]; int bestI[8];
#pragma unroll
    for (int i = 0; i < 8; ++i) { bestD[i] = INFINITY; bestI[i] = 0; }
    for (int ct = 0; ct < COLS_PER_CB; ct += FB_BN) {
        const int c0 = colbase + ct;
        float acc[8][8];
#pragma unroll
        for (int i = 0; i < 8; ++i)
#pragma unroll
            for (int j = 0; j < 8; ++j) acc[i][j] = 0.0f;
        for (int kc = 0; kc < DIM; kc += FB_BK) {
            __syncthreads();
#pragma unroll
            for (int it = 0; it < 4; ++it) {
                int u = it * 256 + tid;
                int r = u >> 3, kg = u & 7;
                float4 a = *(const float4*)&z[(size_t)(row0 + r) * DIM + kc + kg * 4];
                As[kg * 4 + 0][r] = a.x; As[kg * 4 + 1][r] = a.y;
                As[kg * 4 + 2][r] = a.z; As[kg * 4 + 3][r] = a.w;
                float4 b = *(const float4*)&w[(size_t)(c0 + r) * DIM + kc + kg * 4];
                Bs[kg * 4 + 0][r] = b.x; Bs[kg * 4 + 1][r] = b.y;
                Bs[kg * 4 + 2][r] = b.z; Bs[kg * 4 + 3][r] = b.w;
            }
            __syncthreads();
#pragma unroll
            for (int k = 0; k < FB_BK; ++k) {
                float av[8], bv[8];
                { float4 t = *(const float4*)&As[k][rg * 8];
                  av[0]=t.x; av[1]=t.y; av[2]=t.z; av[3]=t.w; }
                { float4 t = *(const float4*)&As[k][rg * 8 + 4];
                  av[4]=t.x; av[5]=t.y; av[6]=t.z; av[7]=t.w; }
                { float4 t = *(const float4*)&Bs[k][cg * 4];
                  bv[0]=t.x; bv[1]=t.y; bv[2]=t.z; bv[3]=t.w; }
                { float4 t = *(const float4*)&Bs[k][cg * 4 + 64];
                  bv[4]=t.x; bv[5]=t.y; bv[6]=t.z; bv[7]=t.w; }
#pragma unroll
                for (int i = 0; i < 8; ++i)
#pragma unroll
                    for (int j = 0; j < 8; ++j)
                        acc[i][j] = fmaf(av[i], bv[j], acc[i][j]);
            }
        }
        float qv[8];
        { float4 t = *(const float4*)&Q[c0 + cg * 4];
          qv[0]=t.x; qv[1]=t.y; qv[2]=t.z; qv[3]=t.w; }
        { float4 t = *(const float4*)&Q[c0 + 64 + cg * 4];
          qv[4]=t.x; qv[5]=t.y; qv[6]=t.z; qv[7]=t.w; }
#pragma unroll
        for (int i = 0; i < 8; ++i)
#pragma unroll
            for (int j = 0; j < 8; ++j) {
                float d = __fsub_rn(__fadd_rn(Pr[i], qv[j]), __fmul_rn(2.0f, acc[i][j]));
                int code = c0 + ((j < 4) ? (cg * 4 + j) : (64 + cg * 4 + (j - 4)));
                if (d < bestD[i]) { bestD[i] = d; bestI[i] = code; }
            }
    }
#pragma unroll
    for (int off = 1; off < 16; off <<= 1)
#pragma unroll
        for (int i = 0; i < 8; ++i) {
            float od = __shfl_xor(bestD[i], off);
            int   oi = __shfl_xor(bestI[i], off);
            if (od < bestD[i] || (od == bestD[i] && oi < bestI[i])) {
                bestD[i] = od; bestI[i] = oi;
            }
        }
    if (cg == 0)
#pragma unroll
        for (int i = 0; i < 8; ++i) {
            int row = row0 + rg * 8 + i;
            cand_d[cb * NROWS + row] = bestD[i];
            cand_i[cb * NROWS + row] = bestI[i];
        }
}

__global__ __launch_bounds__(256) void argmin_reduce_kernel(
    const float* __restrict__ cand_d, const int* __restrict__ cand_i,
    int* __restrict__ idx_i, float* __restrict__ idx_f) {
    const int row = blockIdx.x * 256 + threadIdx.x;
    float bd = cand_d[row];
    int   bi = cand_i[row];
#pragma unroll
    for (int cb = 1; cb < NCB; ++cb) {
        float d = cand_d[cb * NROWS + row];
        int   ii = cand_i[cb * NROWS + row];
        if (d < bd || (d == bd && ii < bi)) { bd = d; bi = ii; }
    }
    idx_i[row] = bi;
    idx_f[row] = (float)bi;
}

extern "C" void kernel_launch(void* const* d_in, const int* in_sizes, int n_in,
                              void* d_out, int out_size, void* d_ws, size_t ws_size,
                              hipStream_t stream) {
    const float* z = (const float*)d_in[0];   // [32768, 256]
    const float* w = (const float*)d_in[1];   // [8192, 256]
    float* out = (float*)d_out;               // [zq 8388608][loss 1][idx 32768]

    float* ws = (float*)d_ws;
    unsigned short* zb = (unsigned short*)ws;                       // 8388608 bf16
    unsigned short* wb = (unsigned short*)(ws + 4194304);           // 2097152 bf16
    float*  P       = ws + 4194304 + 1048576;                       // 32768
    float*  Q       = P + NROWS;                                    // 8192
    int*    idx_i   = (int*)(Q + NCODES);                           // 32768
    double* partial = (double*)(idx_i + NROWS);                     // 8192 dbl
    unsigned long long* keys = (unsigned long long*)(partial + 8192); // 32768 ull
    int*    cnt     = (int*)(keys + NROWS);                         // 32768
    int*    flags   = cnt + NROWS;                                  // 32768
    int*    cand    = flags + NROWS;                                // 32768*64
    const size_t NEED = ((size_t)(4194304 + 1048576 + 32768 + 8192 + 32768 + 16384 + 65536
                                  + 32768 + 32768 + 2097152)) * 4;  // ~30.2 MB

    if (ws_size >= NEED) {
        rowsq_bf16_kernel<<<NROWS / 32, 256, 0, stream>>>(z, P, zb, keys, cnt, flags);
        rowsq_bf16_kernel<<<NCODES / 32, 256, 0, stream>>>(w, Q, wb, nullptr, nullptr, nullptr);
        mfma_filter_kernel<<<(NROWS / BM) * NCB, 256, 0, stream>>>(zb, wb, cnt, cand, flags);
        recheck_kernel<<<NROWS * 32 / 256, 256, 0, stream>>>(z, w, P, Q, cnt, cand,
                                                             flags, keys);
        gather_loss_kernel<<<ZQ_ELEMS / (256 * 4), 256, 0, stream>>>(
            z, w, keys, nullptr, out, out + ZQ_ELEMS + 1, partial);
    } else {
        rowsq_bf16_kernel<<<NROWS / 32, 256, 0, stream>>>(z, P, zb, nullptr, nullptr, nullptr);
        rowsq_bf16_kernel<<<NCODES / 32, 256, 0, stream>>>(w, Q, wb, nullptr, nullptr, nullptr);
        float* cand_d = (float*)(partial + 8192);
        int*   cand_i = (int*)(cand_d + NCB * NROWS);
        vq_partial_kernel<<<(NROWS / FB_BM) * NCB, 256, 0, stream>>>(z, w, P, Q, cand_d, cand_i);
        argmin_reduce_kernel<<<NROWS / 256, 256, 0, stream>>>(cand_d, cand_i, idx_i,
                                                              out + ZQ_ELEMS + 1);
        gather_loss_kernel<<<ZQ_ELEMS / (256 * 4), 256, 0, stream>>>(
            z, w, nullptr, idx_i, out, out + ZQ_ELEMS + 1, partial);
    }

    loss_final_kernel<<<1, 256, 0, stream>>>(partial, out + ZQ_ELEMS);
}

// Round 19
// 458.960 us; speedup vs baseline: 2.0610x; 1.1822x over previous
//
#include <hip/hip_runtime.h>
#include <math.h>

#define DIM     256
#define NROWS   32768
#define NCODES  8192
#define ZQ_ELEMS (NROWS * DIM)   // 8388608

#define CAND_MAX 64
// DELTA covers: ulp(d)~3.05e-5 + bf16 filter error (~50 sigma margin).
// DELAYED-by-one-chunk collection (threshold = running min through chunk ch+1).
#define DELTA    5.0e-4f
#define NCB      4
#define COLS_PER_CB (NCODES / NCB)   // 2048
#define BM 128
#define BN 64
#define CHUNKS (COLS_PER_CB / BN)    // 32
#define LCAP 1984                    // LDS list capacity (total LDS 81.9KB, 2 blk/CU)

typedef __attribute__((ext_vector_type(8))) short bf16x8;
typedef __attribute__((ext_vector_type(4))) float f32x4;

// ---------- explicit RNE float->bf16 ----------
__device__ __forceinline__ unsigned short bf16rne(float x) {
    unsigned u = __float_as_uint(x);
    unsigned r = (u + 0x7FFFu + ((u >> 16) & 1u)) >> 16;
    return (unsigned short)r;
}

// ---------- DPP 16-lane min reduce (VALU-only) ----------
template<int CTRL>
__device__ __forceinline__ float dppmin(float x) {
    int y = __builtin_amdgcn_update_dpp(0, __float_as_int(x), CTRL, 0xF, 0xF, false);
    return fminf(x, __int_as_float(y));
}
__device__ __forceinline__ float rowmin16(float x) {
    x = dppmin<0xB1>(x);    // xor1 (quad_perm 1,0,3,2)
    x = dppmin<0x4E>(x);    // xor2 (quad_perm 2,3,0,1)
    x = dppmin<0x141>(x);   // xor4 (row_half_mirror)
    x = dppmin<0x140>(x);   // xor8 (row_mirror)
    return x;
}

// ---------------- numpy pairwise-sum replication (128-block, 8 accumulators) ---------------
__device__ __forceinline__ float pw128_sq(const float* __restrict__ a) {
    float r[8];
#pragma unroll
    for (int j = 0; j < 8; ++j) r[j] = __fmul_rn(a[j], a[j]);
#pragma unroll
    for (int i = 8; i < 128; i += 8) {
#pragma unroll
        for (int j = 0; j < 8; ++j) r[j] = __fadd_rn(r[j], __fmul_rn(a[i + j], a[i + j]));
    }
    return __fadd_rn(__fadd_rn(__fadd_rn(r[0], r[1]), __fadd_rn(r[2], r[3])),
                     __fadd_rn(__fadd_rn(r[4], r[5]), __fadd_rn(r[6], r[7])));
}

// fused: P[r] = np.sum(x*x) (pairwise, bit-exact) + bf16 conversion write
// + (first 128 blocks) init of keys/cnt/flags.
__global__ __launch_bounds__(256) void rowsq_bf16_kernel(const float* __restrict__ src,
                                                         float* __restrict__ dst,
                                                         unsigned short* __restrict__ bdst,
                                                         unsigned long long* __restrict__ keys,
                                                         int* __restrict__ cnt,
                                                         int* __restrict__ flags) {
    __shared__ float tile[32][DIM + 1];
    const int row0 = blockIdx.x * 32;
    if (keys != nullptr && blockIdx.x < 128) {
        int gid = blockIdx.x * 256 + threadIdx.x;   // covers 32768
        keys[gid] = 0xFFFFFFFFFFFFFFFFull;
        cnt[gid] = 0;
        flags[gid] = 0;
    }
    for (int e = threadIdx.x; e < 32 * DIM / 4; e += 256) {
        int r = e >> 6, c4 = e & 63;
        float4 v = *(const float4*)&src[(size_t)(row0 + r) * DIM + c4 * 4];
        tile[r][c4 * 4 + 0] = v.x; tile[r][c4 * 4 + 1] = v.y;
        tile[r][c4 * 4 + 2] = v.z; tile[r][c4 * 4 + 3] = v.w;
        ushort4 o;
        o.x = bf16rne(v.x); o.y = bf16rne(v.y); o.z = bf16rne(v.z); o.w = bf16rne(v.w);
        ((ushort4*)bdst)[(size_t)(row0 + r) * 64 + c4] = o;
    }
    __syncthreads();
    if (threadIdx.x < 32) {
        const float* a = tile[threadIdx.x];
        float s0 = pw128_sq(a);
        float s1 = pw128_sq(a + 128);
        dst[row0 + threadIdx.x] = __fadd_rn(s0, s1);
    }
}

// ---------- async global->LDS, 16B/lane, wave-uniform LDS base ----------
__device__ __forceinline__ void gload_lds16(const void* g, void* l) {
    __builtin_amdgcn_global_load_lds(
        (const __attribute__((address_space(1))) unsigned int*)g,
        (__attribute__((address_space(3))) unsigned int*)l, 16, 0, 0);
}

// stage a contiguous 32KB region global->LDS with the read-side XOR swizzle
// pre-applied to the SOURCE address. involution: f(x) = x ^ (((x>>9)&7)<<4)
__device__ __forceinline__ void stage32k(const char* gbase, char* lbase,
                                         int wave, int lane) {
#pragma unroll
    for (int it = 0; it < 8; ++it) {
        int ubase = it * 4096 + wave * 1024;          // wave-uniform
        int loff  = ubase + (lane << 4);
        int goff  = loff ^ (((loff >> 9) & 7) << 4);
        gload_lds16(gbase + goff, lbase + ubase);
    }
}

#define WAIT_VM8()  asm volatile("s_waitcnt vmcnt(8)" ::: "memory")
#define WAIT_VM0()  asm volatile("s_waitcnt vmcnt(0)" ::: "memory")
#define LGKM0()     asm volatile("s_waitcnt lgkmcnt(0)" ::: "memory")
#define SBAR()      __builtin_amdgcn_s_barrier()
#define SCHEDB()    __builtin_amdgcn_sched_barrier(0)

// ---------------- MFMA bf16 filter (r13/r16 configuration — 248-255us measured) ----------
// ROW-SPLIT waves; register running-min via DPP; LDS-list collect (delayed one
// chunk). Chunk schedule: MFMA -> LGKM0+SBAR -> stage(ch+2) -> {v-compute,
// DPP min, collect(ch-1)} in the staging shadow -> WAIT_VM8 -> SBAR.
__global__ __launch_bounds__(256, 2) void mfma_filter_kernel(
    const unsigned short* __restrict__ zb, const unsigned short* __restrict__ wb,
    const float* __restrict__ Q,
    int* __restrict__ cnt, int* __restrict__ cand, int* __restrict__ flags) {
    __shared__ __align__(16) unsigned short sbuf[2 * BN * DIM];   // 65536 B
    __shared__ __align__(16) float qlds[COLS_PER_CB];             // 8192 B
    __shared__ unsigned list[LCAP];                               // 7936 B
    __shared__ unsigned lcnt;

    const int tid  = threadIdx.x;
    const int wave = tid >> 6;
    const int lane = tid & 63;
    const int l15 = lane & 15, lg = lane >> 4;
    const int bid = blockIdx.x;
    const int r8  = bid & 7;
    const int cb  = r8 >> 1;                        // 0..3
    const int rb  = ((bid >> 3) << 1) | (r8 & 1);   // 0..255
    const int row0 = rb * BM;
    const int colbase = cb * COLS_PER_CB;
    const int swz = (l15 & 7) << 4;

    if (tid == 0) lcnt = 0;

    // ---- A fragments: direct global->registers, non-temporal ----
    bf16x8 afr[2][8];
    const unsigned short* za = zb + (size_t)(row0 + wave * 32 + l15) * DIM + lg * 8;
#pragma unroll
    for (int fr = 0; fr < 2; ++fr)
#pragma unroll
        for (int kc = 0; kc < 8; ++kc)
            afr[fr][kc] = __builtin_nontemporal_load(
                (const bf16x8*)(za + (size_t)fr * 16 * DIM + kc * 32));
    SCHEDB();   // pin A-load issue before staging (vmcnt arithmetic)

    // ---- Q range -> LDS (2 x 16B/lane, linear) ----
#pragma unroll
    for (int it = 0; it < 2; ++it) {
        int ubase = it * 4096 + wave * 1024;
        gload_lds16((const char*)(Q + colbase) + ubase + (lane << 4),
                    (char*)qlds + ubase);
    }
    // ---- prologue: issue B0, B1 ----
    stage32k((const char*)(wb + ((size_t)colbase << 8)), (char*)sbuf, wave, lane);
    stage32k((const char*)(wb + ((size_t)(colbase + BN) << 8)),
             (char*)sbuf + 32768, wave, lane);
    LGKM0();               // lcnt init visible
    WAIT_VM8();            // A(16)+Q(2)+B0(8) complete; B1 (8) outstanding
    SCHEDB();
    SBAR();                // blockwide: B0 + qlds ready
    SCHEDB();

    float rmn[2][4];       // register running min per (fr,j) — uniform in l15 group
#pragma unroll
    for (int fr = 0; fr < 2; ++fr)
#pragma unroll
        for (int j = 0; j < 4; ++j) rmn[fr][j] = INFINITY;

    f32x4 pacc[2][4];      // previous chunk's v values (delayed collection)
    float pmn[2][4];       // previous chunk's per-lane fc-min (collect guard)

#pragma unroll 1
    for (int ch = 0; ch < CHUNKS; ++ch) {
        const char* bb = (const char*)sbuf + ((ch & 1) << 15);

        f32x4 acc[2][4];
#pragma unroll
        for (int fr = 0; fr < 2; ++fr)
#pragma unroll
            for (int fc = 0; fc < 4; ++fc) acc[fr][fc] = (f32x4){0.f, 0.f, 0.f, 0.f};

        __builtin_amdgcn_s_setprio(1);
#pragma unroll
        for (int kc = 0; kc < 8; ++kc) {
            bf16x8 bfr[4];
#pragma unroll
            for (int fc = 0; fc < 4; ++fc)
                bfr[fc] = *(const bf16x8*)(bb +
                    ((((fc * 16 + l15) << 9) + (kc << 6) + (lg << 4)) ^ swz));
#pragma unroll
            for (int fr = 0; fr < 2; ++fr)
#pragma unroll
                for (int fc = 0; fc < 4; ++fc)
                    acc[fr][fc] = __builtin_amdgcn_mfma_f32_16x16x32_bf16(
                        afr[fr][kc], bfr[fc], acc[fr][fc], 0, 0, 0);
        }
        __builtin_amdgcn_s_setprio(0);

        LGKM0();           // all bb ds_reads complete (wave-local)
        SCHEDB();
        SBAR();            // blockwide: bb safe to overwrite
        SCHEDB();

        // issue next stage FIRST — epilogue below runs in its shadow
        if (ch + 2 < CHUNKS)
            stage32k((const char*)(wb + ((size_t)(colbase + (ch + 2) * BN) << 8)),
                     (char*)sbuf + ((ch & 1) << 15), wave, lane);

        // v = Q - 2*S (Q from LDS — lgkmcnt, not vmcnt)
        float qv[4];
#pragma unroll
        for (int fc = 0; fc < 4; ++fc) qv[fc] = qlds[ch * BN + fc * 16 + l15];
#pragma unroll
        for (int fr = 0; fr < 2; ++fr)
#pragma unroll
            for (int fc = 0; fc < 4; ++fc)
#pragma unroll
                for (int j = 0; j < 4; ++j)
                    acc[fr][fc][j] = qv[fc] - 2.0f * acc[fr][fc][j];

        // per-lane fc-min, then DPP 16-lane reduce -> running min (VALU only)
        float lmn[2][4];
#pragma unroll
        for (int fr = 0; fr < 2; ++fr)
#pragma unroll
            for (int j = 0; j < 4; ++j) {
                lmn[fr][j] = fminf(fminf(acc[fr][0][j], acc[fr][1][j]),
                                   fminf(acc[fr][2][j], acc[fr][3][j]));
                rmn[fr][j] = fminf(rmn[fr][j], rowmin16(lmn[fr][j]));
            }

        // DELAYED collection: chunk ch-1's v vs reg-min through chunk ch.
        if (ch > 0) {
            const int code0 = colbase + (ch - 1) * BN;
#pragma unroll
            for (int fr = 0; fr < 2; ++fr)
#pragma unroll
                for (int j = 0; j < 4; ++j) {
                    float thr = rmn[fr][j] + DELTA;
                    if (pmn[fr][j] <= thr) {   // lane guard: skip lanes w/o candidates
                        const int rl = wave * 32 + fr * 16 + lg * 4 + j;
#pragma unroll
                        for (int fc = 0; fc < 4; ++fc) {
                            if (pacc[fr][fc][j] <= thr) {
                                int code = code0 + fc * 16 + l15;
                                unsigned s = atomicAdd(&lcnt, 1u);
                                if (s < LCAP) {
                                    list[s] = ((unsigned)rl << 13) | (unsigned)code;
                                } else {   // graceful spill (rare)
                                    int row = row0 + rl;
                                    int slot = atomicAdd(&cnt[row], 1);
                                    if (slot < CAND_MAX)
                                        cand[(size_t)row * CAND_MAX + slot] = code;
                                    else flags[row] = 1;
                                }
                            }
                        }
                    }
                }
        }
#pragma unroll
        for (int fr = 0; fr < 2; ++fr) {
#pragma unroll
            for (int fc = 0; fc < 4; ++fc) pacc[fr][fc] = acc[fr][fc];
#pragma unroll
            for (int j = 0; j < 4; ++j) pmn[fr][j] = lmn[fr][j];
        }

        // ---- pipeline advance: counted vmcnt, no full drain ----
        if (ch + 2 < CHUNKS) {
            WAIT_VM8();    // B[ch+1] landed; B[ch+2] still in flight
        } else {
            WAIT_VM0();    // tail: drain
        }
        SCHEDB();
        SBAR();            // blockwide: next buffer ready
        SCHEDB();
    }

    // final chunk's candidates vs the FINAL running min
    {
        const int code0 = colbase + (CHUNKS - 1) * BN;
#pragma unroll
        for (int fr = 0; fr < 2; ++fr)
#pragma unroll
            for (int j = 0; j < 4; ++j) {
                float thr = rmn[fr][j] + DELTA;
                if (pmn[fr][j] <= thr) {
                    const int rl = wave * 32 + fr * 16 + lg * 4 + j;
#pragma unroll
                    for (int fc = 0; fc < 4; ++fc) {
                        if (pacc[fr][fc][j] <= thr) {
                            int code = code0 + fc * 16 + l15;
                            unsigned s = atomicAdd(&lcnt, 1u);
                            if (s < LCAP) {
                                list[s] = ((unsigned)rl << 13) | (unsigned)code;
                            } else {
                                int row = row0 + rl;
                                int slot = atomicAdd(&cnt[row], 1);
                                if (slot < CAND_MAX)
                                    cand[(size_t)row * CAND_MAX + slot] = code;
                                else flags[row] = 1;
                            }
                        }
                    }
                }
            }
    }

    // ---- flush LDS candidate list to global ----
    LGKM0();
    SCHEDB();
    SBAR();
    SCHEDB();
    unsigned n = lcnt;
    if (n > LCAP) n = LCAP;
    for (unsigned i = tid; i < n; i += 256) {
        unsigned e = list[i];
        int rl = (int)(e >> 13);
        int code = (int)(e & 8191u);
        int row = row0 + rl;
        int slot = atomicAdd(&cnt[row], 1);
        if (slot < CAND_MAX) cand[(size_t)row * CAND_MAX + slot] = code;
        else flags[row] = 1;
    }
}

// ---------------- exact recheck: ascending-k fmaf chain, lexicographic atomicMin ----------------
__device__ __forceinline__ float exact_dot(const float* __restrict__ zr,
                                           const float* __restrict__ wj) {
    const f32x4* z4 = (const f32x4*)zr;
    const f32x4* w4 = (const f32x4*)wj;
    float m = 0.0f;
#pragma unroll 8
    for (int k4 = 0; k4 < 64; ++k4) {     // same ascending-k single chain, bit-exact
        f32x4 a = z4[k4], b = w4[k4];
        m = fmaf(a[0], b[0], m);
        m = fmaf(a[1], b[1], m);
        m = fmaf(a[2], b[2], m);
        m = fmaf(a[3], b[3], m);
    }
    return m;
}

// 32 slots/row; slot-stride loop handles n up to CAND_MAX.
__global__ __launch_bounds__(256) void recheck_kernel(
    const float* __restrict__ z, const float* __restrict__ w,
    const float* __restrict__ P, const float* __restrict__ Q,
    const int* __restrict__ cnt, const int* __restrict__ cand,
    const int* __restrict__ flags, unsigned long long* __restrict__ keys) {
    const int gid  = blockIdx.x * 256 + threadIdx.x;
    const int row  = gid >> 5;         // 32 slots per row
    const int slot = gid & 31;
    const float* zr = z + (size_t)row * DIM;

    if (flags[row]) {
        for (int j = slot; j < NCODES; j += 32) {
            float m = exact_dot(zr, w + (size_t)j * DIM);
            float d = __fsub_rn(__fadd_rn(P[row], Q[j]), __fmul_rn(2.0f, m));
            unsigned long long key =
                ((unsigned long long)__float_as_uint(d) << 32) | (unsigned)j;
            atomicMin(&keys[row], key);
        }
        return;
    }
    int n = cnt[row]; if (n > CAND_MAX) n = CAND_MAX;
    for (int s = slot; s < n; s += 32) {
        const int j = cand[(size_t)row * CAND_MAX + s];
        float m = exact_dot(zr, w + (size_t)j * DIM);
        float d = __fsub_rn(__fadd_rn(P[row], Q[j]), __fmul_rn(2.0f, m));
        unsigned long long key = ((unsigned long long)__float_as_uint(d) << 32) | (unsigned)j;
        atomicMin(&keys[row], key);
    }
}

// ---------------- gather z_q, write z_q_st + idx_f (fused finalize), loss partials -------------
__global__ __launch_bounds__(256) void gather_loss_kernel(
    const float* __restrict__ z, const float* __restrict__ w,
    const unsigned long long* __restrict__ keys, const int* __restrict__ idx_i,
    float* __restrict__ zq_out, float* __restrict__ idx_f,
    double* __restrict__ partial) {
    __shared__ double red[256];
    const int t    = blockIdx.x * 256 + threadIdx.x;
    const int base = t * 4;
    const int row  = base >> 8;
    const int c    = base & 255;
    int code;
    if (keys != nullptr) code = (int)(unsigned)(keys[row] & 0xFFFFFFFFull);
    else                 code = idx_i[row];
    if (c == 0) idx_f[row] = (float)code;
    f32x4 zv = __builtin_nontemporal_load((const f32x4*)&z[base]);
    f32x4 wv = *(const f32x4*)&w[(size_t)code * DIM + c];
    float o[4];
    double s = 0.0;
#pragma unroll
    for (int j = 0; j < 4; ++j) {
        float diff = __fsub_rn(wv[j], zv[j]);
        o[j] = __fadd_rn(zv[j], diff);
        double dd = (double)diff;
        s += dd * dd;
    }
    f32x4 ov = { o[0], o[1], o[2], o[3] };
    __builtin_nontemporal_store(ov, (f32x4*)&zq_out[base]);
    red[threadIdx.x] = s;
    __syncthreads();
    for (int st = 128; st > 0; st >>= 1) {
        if (threadIdx.x < st) red[threadIdx.x] += red[threadIdx.x + st];
        __syncthreads();
    }
    if (threadIdx.x == 0) partial[blockIdx.x] = red[0];
}

__global__ __launch_bounds__(256) void loss_final_kernel(const double* __restrict__ partial,
                                                         float* __restrict__ loss_out) {
    __shared__ double red[256];
    double s = 0.0;
    for (int i = threadIdx.x; i < 8192; i += 256) s += partial[i];
    red[threadIdx.x] = s;
    __syncthreads();
    for (int st = 128; st > 0; st >>= 1) {
        if (threadIdx.x < st) red[threadIdx.x] += red[threadIdx.x + st];
        __syncthreads();
    }
    if (threadIdx.x == 0)
        loss_out[0] = (float)(1.25 * red[0] / (double)ZQ_ELEMS);
}

// ---------------- small-ws fallback: round-2 exact VALU kernel ----------------
#define FB_BM 128
#define FB_BN 128
#define FB_BK 32
#define FB_PITCH 132

__global__ __launch_bounds__(256, 4) void vq_partial_kernel(
    const float* __restrict__ z, const float* __restrict__ w,
    const float* __restrict__ P, const float* __restrict__ Q,
    float* __restrict__ cand_d, int* __restrict__ cand_i) {
    __shared__ float As[FB_BK][FB_PITCH];
    __shared__ float Bs[FB_BK][FB_PITCH];
    const int tid  = threadIdx.x;
    const int rb   = blockIdx.x >> 2;
    const int cb   = blockIdx.x & 3;
    const int row0 = rb * FB_BM;
    const int colbase = cb * COLS_PER_CB;
    const int rg = tid >> 4;
    const int cg = tid & 15;
    float Pr[8];
#pragma unroll
    for (int i = 0; i < 8; ++i) Pr[i] = P[row0 + rg * 8 + i];
    float bestD[8]; int bestI[8];
#pragma unroll
    for (int i = 0; i < 8; ++i) { bestD[i] = INFINITY; bestI[i] = 0; }
    for (int ct = 0; ct < COLS_PER_CB; ct += FB_BN) {
        const int c0 = colbase + ct;
        float acc[8][8];
#pragma unroll
        for (int i = 0; i < 8; ++i)
#pragma unroll
            for (int j = 0; j < 8; ++j) acc[i][j] = 0.0f;
        for (int kc = 0; kc < DIM; kc += FB_BK) {
            __syncthreads();
#pragma unroll
            for (int it = 0; it < 4; ++it) {
                int u = it * 256 + tid;
                int r = u >> 3, kg = u & 7;
                float4 a = *(const float4*)&z[(size_t)(row0 + r) * DIM + kc + kg * 4];
                As[kg * 4 + 0][r] = a.x; As[kg * 4 + 1][r] = a.y;
                As[kg * 4 + 2][r] = a.z; As[kg * 4 + 3][r] = a.w;
                float4 b = *(const float4*)&w[(size_t)(c0 + r) * DIM + kc + kg * 4];
                Bs[kg * 4 + 0][r] = b.x; Bs[kg * 4 + 1][r] = b.y;
                Bs[kg * 4 + 2][r] = b.z; Bs[kg * 4 + 3][r] = b.w;
            }
            __syncthreads();
#pragma unroll
            for (int k = 0; k < FB_BK; ++k) {
                float av[8], bv[8];
                { float4 t = *(const float4*)&As[k][rg * 8];
                  av[0]=t.x; av[1]=t.y; av[2]=t.z; av[3]=t.w; }
                { float4 t = *(const float4*)&As[k][rg * 8 + 4];
                  av[4]=t.x; av[5]=t.y; av[6]=t.z; av[7]=t.w; }
                { float4 t = *(const float4*)&Bs[k][cg * 4];
                  bv[0]=t.x; bv[1]=t.y; bv[2]=t.z; bv[3]=t.w; }
                { float4 t = *(const float4*)&Bs[k][cg * 4 + 64];
                  bv[4]=t.x; bv[5]=t.y; bv[6]=t.z; bv[7]=t.w; }
#pragma unroll
                for (int i = 0; i < 8; ++i)
#pragma unroll
                    for (int j = 0; j < 8; ++j)
                        acc[i][j] = fmaf(av[i], bv[j], acc[i][j]);
            }
        }
        float qv[8];
        { float4 t = *(const float4*)&Q[c0 + cg * 4];
          qv[0]=t.x; qv[1]=t.y; qv[2]=t.z; qv[3]=t.w; }
        { float4 t = *(const float4*)&Q[c0 + 64 + cg * 4];
          qv[4]=t.x; qv[5]=t.y; qv[6]=t.z; qv[7]=t.w; }
#pragma unroll
        for (int i = 0; i < 8; ++i)
#pragma unroll
            for (int j = 0; j < 8; ++j) {
                float d = __fsub_rn(__fadd_rn(Pr[i], qv[j]), __fmul_rn(2.0f, acc[i][j]));
                int code = c0 + ((j < 4) ? (cg * 4 + j) : (64 + cg * 4 + (j - 4)));
                if (d < bestD[i]) { bestD[i] = d; bestI[i] = code; }
            }
    }
#pragma unroll
    for (int off = 1; off < 16; off <<= 1)
#pragma unroll
        for (int i = 0; i < 8; ++i) {
            float od = __shfl_xor(bestD[i], off);
            int   oi = __shfl_xor(bestI[i], off);
            if (od < bestD[i] || (od == bestD[i] && oi < bestI[i])) {
                bestD[i] = od; bestI[i] = oi;
            }
        }
    if (cg == 0)
#pragma unroll
        for (int i = 0; i < 8; ++i) {
            int row = row0 + rg * 8 + i;
            cand_d[cb * NROWS + row] = bestD[i];
            cand_i[cb * NROWS + row] = bestI[i];
        }
}

__global__ __launch_bounds__(256) void argmin_reduce_kernel(
    const float* __restrict__ cand_d, const int* __restrict__ cand_i,
    int* __restrict__ idx_i, float* __restrict__ idx_f) {
    const int row = blockIdx.x * 256 + threadIdx.x;
    float bd = cand_d[row];
    int   bi = cand_i[row];
#pragma unroll
    for (int cb = 1; cb < NCB; ++cb) {
        float d = cand_d[cb * NROWS + row];
        int   ii = cand_i[cb * NROWS + row];
        if (d < bd || (d == bd && ii < bi)) { bd = d; bi = ii; }
    }
    idx_i[row] = bi;
    idx_f[row] = (float)bi;
}

extern "C" void kernel_launch(void* const* d_in, const int* in_sizes, int n_in,
                              void* d_out, int out_size, void* d_ws, size_t ws_size,
                              hipStream_t stream) {
    const float* z = (const float*)d_in[0];   // [32768, 256]
    const float* w = (const float*)d_in[1];   // [8192, 256]
    float* out = (float*)d_out;               // [zq 8388608][loss 1][idx 32768]

    float* ws = (float*)d_ws;
    unsigned short* zb = (unsigned short*)ws;                       // 8388608 bf16
    unsigned short* wb = (unsigned short*)(ws + 4194304);           // 2097152 bf16
    float*  P       = ws + 4194304 + 1048576;                       // 32768
    float*  Q       = P + NROWS;                                    // 8192
    int*    idx_i   = (int*)(Q + NCODES);                           // 32768
    double* partial = (double*)(idx_i + NROWS);                     // 8192 dbl
    unsigned long long* keys = (unsigned long long*)(partial + 8192); // 32768 ull
    int*    cnt     = (int*)(keys + NROWS);                         // 32768
    int*    flags   = cnt + NROWS;                                  // 32768
    int*    cand    = flags + NROWS;                                // 32768*64
    const size_t NEED = ((size_t)(4194304 + 1048576 + 32768 + 8192 + 32768 + 16384 + 65536
                                  + 32768 + 32768 + 2097152)) * 4;  // ~30.2 MB

    if (ws_size >= NEED) {
        rowsq_bf16_kernel<<<NROWS / 32, 256, 0, stream>>>(z, P, zb, keys, cnt, flags);
        rowsq_bf16_kernel<<<NCODES / 32, 256, 0, stream>>>(w, Q, wb, nullptr, nullptr, nullptr);
        mfma_filter_kernel<<<(NROWS / BM) * NCB, 256, 0, stream>>>(zb, wb, Q, cnt, cand, flags);
        recheck_kernel<<<NROWS * 32 / 256, 256, 0, stream>>>(z, w, P, Q, cnt, cand,
                                                             flags, keys);
        gather_loss_kernel<<<ZQ_ELEMS / (256 * 4), 256, 0, stream>>>(
            z, w, keys, nullptr, out, out + ZQ_ELEMS + 1, partial);
    } else {
        rowsq_bf16_kernel<<<NROWS / 32, 256, 0, stream>>>(z, P, zb, nullptr, nullptr, nullptr);
        rowsq_bf16_kernel<<<NCODES / 32, 256, 0, stream>>>(w, Q, wb, nullptr, nullptr, nullptr);
        float* cand_d = (float*)(partial + 8192);
        int*   cand_i = (int*)(cand_d + NCB * NROWS);
        vq_partial_kernel<<<(NROWS / FB_BM) * NCB, 256, 0, stream>>>(z, w, P, Q, cand_d, cand_i);
        argmin_reduce_kernel<<<NROWS / 256, 256, 0, stream>>>(cand_d, cand_i, idx_i,
                                                              out + ZQ_ELEMS + 1);
        gather_loss_kernel<<<ZQ_ELEMS / (256 * 4), 256, 0, stream>>>(
            z, w, nullptr, idx_i, out, out + ZQ_ELEMS + 1, partial);
    }

    loss_final_kernel<<<1, 256, 0, stream>>>(partial, out + ZQ_ELEMS);
}